// Round 12
// baseline (339.612 us; speedup 1.0000x reference)
//
#include <hip/hip_runtime.h>

// Problem constants
#define N_NODES 25000
#define N_EDGES 200000
// MUL=16, NUM_RADIAL=8, HIDDEN=64, WNUMEL=1024
// PATH_ALPHA=1/sqrt(32), INV_SQRT3=1/sqrt(3), scales folded into B-fragments.

constexpr int ET = 16;      // edges per tile
constexpr int NT = 10;      // tiles per block
constexpr int NBLK = 1250;  // 1250*10*16 = 200000 edges exactly

typedef __attribute__((ext_vector_type(8))) _Float16 half8;  // 8 f16 (4 VGPR)
typedef __attribute__((ext_vector_type(4))) float float4v;   // 4 fp32

__device__ __forceinline__ half8 h8s(half8 a, _Float16 c) { return a * c; }  // v_pk_mul_f16 x4

// Same-wave LDS ordering fence: waits for this wave's outstanding LDS ops and
// stops the compiler reordering memory ops across it. No inter-wave semantics.
__device__ __forceinline__ void lds_fence() {
    asm volatile("s_waitcnt lgkmcnt(0)" ::: "memory");
}

// ---------------- self-connection (round-9 verified version) ----------------
__global__ __launch_bounds__(256) void sc_kernel(const float* __restrict__ x,
                                                 const float* __restrict__ L0,
                                                 const float* __restrict__ L1,
                                                 float* __restrict__ out) {
    __shared__ float l0[256], l1[256];
    __shared__ float xs[4][68];
    const int t = threadIdx.x;
    l0[t] = L0[t];
    l1[t] = L1[t];
    const int g = t >> 6, j = t & 63;
    const int n = blockIdx.x * 4 + g;          // 6250 blocks x 4 nodes
    xs[g][j] = x[n * 64 + j];                  // coalesced
    __syncthreads();
    float s = 0.f;
    if (j < 16) {
        #pragma unroll
        for (int u = 0; u < 16; ++u) s = fmaf(xs[g][u], l0[u * 16 + j], s);
    } else {
        const int q = j - 16, v = q / 3, k = q - 3 * v;
        #pragma unroll
        for (int u = 0; u < 16; ++u) s = fmaf(xs[g][16 + 3 * u + k], l1[u * 16 + v], s);
    }
    out[n * 64 + j] = 0.25f * s;   // 1/sqrt(MUL)
}

// ---------------- edge kernel: wave-private, barrier-free main loop ----------------
// 256 threads = 4 independent waves, all processing the SAME 16-edge tiles:
//   wave role: m01 = (w>>1)  (0: m0 output, progs 0+1; 1: m1 output, progs 2+3)
//              uh  = (w&1)   (u-half; halves combine via the output atomics)
// Each wave stages x/meta into its OWN LDS slice (same-wave DS ordering),
// computes h + coefs itself, runs its MFMA chain, atomics out. No __syncthreads
// in the loop -> no vmcnt drains, latencies overlap freely across 8 waves/CU.
__global__ __launch_bounds__(256, 2) void edge_kernel(
    const float* __restrict__ x, const float* __restrict__ edge_attr,
    const float* __restrict__ edge_length, const int* __restrict__ edge_src,
    const int* __restrict__ edge_dst, const float* __restrict__ W1,
    const float* __restrict__ W2, float* __restrict__ out) {

    const int t = threadIdx.x;
    const int w = t >> 6;             // wave id 0..3
    const int m01 = w >> 1;           // 0: m0, 1: m1
    const int uh = w & 1;             // u-half
    const int l = t & 63;
    const int qm = l & 15;            // MFMA m/n index (edge for A/C, v for B)
    const int quad = (l >> 4) & 3;    // lane quad
    const int e16 = l >> 2;           // staging: edge index (4 lanes/edge)
    const int part = l & 3;           // staging: 16-float chunk within row

    __shared__ __attribute__((aligned(16))) _Float16 w1h[64 * 8];   // W1^T f16 [c][r]
    __shared__ __attribute__((aligned(16))) float xs[4][ET * 68];   // per-wave x rows
    __shared__ __attribute__((aligned(16))) float meta[4][ET * 8];  // per-wave: sh0..3,len,dstbits

    // ---- persistent B fragments: the role's 2 W2 blocks, u-half, pre-scaled f16 ----
    // B-frag layout (16x16x32): lane holds B[k = kf*32 + quad*8 + j][n = qm]
    half8 bfr[2][8][2];               // [prog-in-pair][u'][kf]  = 128 VGPR
    {
        const int kr = quad * 8;
        #pragma unroll
        for (int pp = 0; pp < 2; ++pp) {
            const int prog = m01 * 2 + pp;
            float scale = 0.0220970869f;              // (1/sqrt(64)) * (1/sqrt(32))
            if (prog == 1) scale *= 0.5773502692f;    // INV_SQRT3 folded
            #pragma unroll
            for (int up = 0; up < 8; ++up) {
                const int col = prog * 256 + (uh * 8 + up) * 16 + qm;
                #pragma unroll
                for (int kf = 0; kf < 2; ++kf) {
                    half8 f;
                    #pragma unroll
                    for (int j = 0; j < 8; ++j) {
                        const int k = kf * 32 + kr + j;
                        f[j] = (_Float16)(W2[k * 1024 + col] * scale);
                    }
                    bfr[pp][up][kf] = f;
                }
            }
        }
    }
    // W1^T -> f16 LDS [c][r] (read-only after the single barrier)
    for (int i = t; i < 512; i += 256) {
        const int r = i >> 6, c = i & 63;
        w1h[c * 8 + r] = (_Float16)W1[i];
    }
    __syncthreads();   // the ONLY block barrier

    float* const myxs = xs[w];
    float* const mymeta = meta[w];

    // ---- initial prefetch (tile 0) ----
    const int ebase = blockIdx.x * NT * ET;
    int     pf_src = edge_src[ebase + e16];
    float4v pf_ea; float pf_len = 0.f; int pf_dst = 0;
    if (l < ET) {
        pf_dst = edge_dst[ebase + l];
        pf_len = edge_length[ebase + l];
        pf_ea  = *(const float4v*)(edge_attr + 4 * (ebase + l));
    }
    float4v pf_x[4];
    #pragma unroll
    for (int i = 0; i < 4; ++i)
        pf_x[i] = *(const float4v*)(x + pf_src * 64 + part * 16 + i * 4);

    for (int tl = 0; tl < NT; ++tl) {
        // ---- commit prefetched tile into wave-private LDS ----
        #pragma unroll
        for (int i = 0; i < 4; ++i)
            *(float4v*)(&myxs[e16 * 68 + part * 16 + i * 4]) = pf_x[i];
        if (l < ET) {
            *(float4v*)(&mymeta[l * 8]) = pf_ea;      // sh0, sh1x, sh1y, sh1z
            mymeta[l * 8 + 4] = pf_len;
            mymeta[l * 8 + 5] = __int_as_float(pf_dst);
        }
        lds_fence();   // this wave's writes complete before its reads below

        // ---- issue next tile's src/meta prefetch ----
        const int e0n = ebase + ((tl + 1 < NT) ? (tl + 1) : 0) * ET;
        const int nsrc = edge_src[e0n + e16];
        if (l < ET) {
            pf_dst = edge_dst[e0n + l];
            pf_len = edge_length[e0n + l];
            pf_ea  = *(const float4v*)(edge_attr + 4 * (e0n + l));
        }

        // ---- h for edge qm, k-slices [quad*8..+7] and [32+quad*8..+7] ----
        const float len = mymeta[qm * 8 + 4];
        float rad[8];
        #pragma unroll
        for (int r = 0; r < 8; ++r) {
            const float d = len - 0.7142857143f * (float)r;
            rad[r] = __expf(-0.5f * d * d);
        }
        half8 ah0, ah1;
        #pragma unroll
        for (int s = 0; s < 2; ++s) {
            #pragma unroll
            for (int j = 0; j < 8; ++j) {
                const int c = s * 32 + quad * 8 + j;
                const half8 wc = *(const half8*)(&w1h[c * 8]);   // 8 f16 = 1 b128
                float acc = 0.f;
                #pragma unroll
                for (int r = 0; r < 8; ++r) acc = fmaf(rad[r], (float)wc[r], acc);
                acc *= 0.3535533906f;
                const float hval = acc / (1.f + __expf(-acc));
                if (s == 0) ah0[j] = (_Float16)hval; else ah1[j] = (_Float16)hval;
            }
        }

        // ---- coefficients for edge qm, u-half ----
        const float4v sh = *(const float4v*)(&mymeta[qm * 8]);   // sh0, sh1xyz
        float xj0[8];
        {
            const float4v a = *(const float4v*)(&myxs[qm * 68 + uh * 8]);
            const float4v b = *(const float4v*)(&myxs[qm * 68 + uh * 8 + 4]);
            #pragma unroll
            for (int i = 0; i < 4; ++i) { xj0[i] = a[i]; xj0[4 + i] = b[i]; }
        }
        float xj1[24];
        #pragma unroll
        for (int i = 0; i < 6; ++i) {
            const float4v v4 = *(const float4v*)(&myxs[qm * 68 + 16 + uh * 24 + i * 4]);
            #pragma unroll
            for (int j = 0; j < 4; ++j) xj1[i * 4 + j] = v4[j];
        }

        // ---- issue next tile's x prefetch (nsrc has had ~600 cyc) ----
        #pragma unroll
        for (int i = 0; i < 4; ++i)
            pf_x[i] = *(const float4v*)(x + nsrc * 64 + part * 16 + i * 4);
        pf_src = nsrc;

        // ---- MFMA + epilogue (wave-private; atomics combine everything) ----
        // C layout: col v = qm, row e = quad*4 + r
        if (m01 == 0) {
            // m0[e][v] += sum_{u in half} (xj0*sh0)[u]*(h W2_0u)[v] + b1[u]*(h W2_1u)[v]
            float4v a0 = (float4v){0.f,0.f,0.f,0.f};
            float4v a1 = (float4v){0.f,0.f,0.f,0.f};
            #pragma unroll
            for (int up = 0; up < 8; ++up) {
                const _Float16 c0 = (_Float16)(xj0[up] * sh[0]);
                const _Float16 c1 = (_Float16)(xj1[3*up]*sh[1] + xj1[3*up+1]*sh[2] + xj1[3*up+2]*sh[3]);
                a0 = __builtin_amdgcn_mfma_f32_16x16x32_f16(h8s(ah0, c0), bfr[0][up][0], a0, 0, 0, 0);
                a0 = __builtin_amdgcn_mfma_f32_16x16x32_f16(h8s(ah1, c0), bfr[0][up][1], a0, 0, 0, 0);
                a1 = __builtin_amdgcn_mfma_f32_16x16x32_f16(h8s(ah0, c1), bfr[1][up][0], a1, 0, 0, 0);
                a1 = __builtin_amdgcn_mfma_f32_16x16x32_f16(h8s(ah1, c1), bfr[1][up][1], a1, 0, 0, 0);
            }
            #pragma unroll
            for (int r = 0; r < 4; ++r) {
                const int e = quad * 4 + r;
                const int dst = __float_as_int(mymeta[e * 8 + 5]);
                atomicAdd(out + dst * 64 + qm, a0[r] + a1[r]);
            }
        } else {
            // m1[e][v][k] += sh1[k]*sum_u xj0[u]*(h W2_2u)[v] + sum_u (xj1[u,k]*sh0)*(h W2_3u)[v]
            float4v a2 = (float4v){0.f,0.f,0.f,0.f};
            float4v a3[3];
            a3[0] = (float4v){0.f,0.f,0.f,0.f};
            a3[1] = (float4v){0.f,0.f,0.f,0.f};
            a3[2] = (float4v){0.f,0.f,0.f,0.f};
            #pragma unroll
            for (int up = 0; up < 8; ++up) {
                const _Float16 c2 = (_Float16)xj0[up];
                a2 = __builtin_amdgcn_mfma_f32_16x16x32_f16(h8s(ah0, c2), bfr[0][up][0], a2, 0, 0, 0);
                a2 = __builtin_amdgcn_mfma_f32_16x16x32_f16(h8s(ah1, c2), bfr[0][up][1], a2, 0, 0, 0);
                #pragma unroll
                for (int k = 0; k < 3; ++k) {
                    const _Float16 c3 = (_Float16)(xj1[3*up + k] * sh[0]);
                    a3[k] = __builtin_amdgcn_mfma_f32_16x16x32_f16(h8s(ah0, c3), bfr[1][up][0], a3[k], 0, 0, 0);
                    a3[k] = __builtin_amdgcn_mfma_f32_16x16x32_f16(h8s(ah1, c3), bfr[1][up][1], a3[k], 0, 0, 0);
                }
            }
            #pragma unroll
            for (int r = 0; r < 4; ++r) {
                const int e = quad * 4 + r;
                const int dst = __float_as_int(mymeta[e * 8 + 5]);
                float* op = out + dst * 64 + 16 + qm * 3;
                #pragma unroll
                for (int k = 0; k < 3; ++k)
                    atomicAdd(op + k, mymeta[e * 8 + 1 + k] * a2[r] + a3[k][r]);
            }
        }
        // Next iteration's LDS commit only depends on this wave's own reads
        // being done (in-order DS) -- no barrier, atomics never drained.
    }
}

extern "C" void kernel_launch(void* const* d_in, const int* in_sizes, int n_in,
                              void* d_out, int out_size, void* d_ws, size_t ws_size,
                              hipStream_t stream) {
    const float* x           = (const float*)d_in[0];
    const float* edge_attr   = (const float*)d_in[1];
    const float* edge_length = (const float*)d_in[2];
    const int*   edge_src    = (const int*)d_in[3];
    const int*   edge_dst    = (const int*)d_in[4];
    const float* W1          = (const float*)d_in[5];
    const float* W2          = (const float*)d_in[6];
    const float* L0          = (const float*)d_in[7];
    const float* L1          = (const float*)d_in[8];
    float* out = (float*)d_out;

    sc_kernel<<<N_NODES / 4, 256, 0, stream>>>(x, L0, L1, out);
    edge_kernel<<<NBLK, 256, 0, stream>>>(
        x, edge_attr, edge_length, edge_src, edge_dst, W1, W2, out);
}

// Round 13
// 293.654 us; speedup vs baseline: 1.1565x; 1.1565x over previous
//
#include <hip/hip_runtime.h>

// Problem constants
#define N_NODES 25000
#define N_EDGES 200000
// MUL=16, NUM_RADIAL=8, HIDDEN=64, WNUMEL=1024
// PATH_ALPHA=1/sqrt(32), INV_SQRT3=1/sqrt(3), scales folded into B-fragments.

constexpr int ET = 32;      // edges per tile
constexpr int NT = 5;       // tiles per block
constexpr int NBLK = 1250;  // 1250*5*32 = 200000 edges exactly
constexpr int CAP = 48;     // per-node edge-slot capacity (Poisson(8): P(deg>48) ~ 0)

typedef __attribute__((ext_vector_type(8))) _Float16 half8;  // 8 f16 (4 VGPR)
typedef __attribute__((ext_vector_type(4))) float float4v;   // 4 fp32

__device__ __forceinline__ half8 h8s(half8 a, _Float16 c) { return a * c; }  // v_pk_mul_f16 x4

// ---------------- self-connection (fallback path; round-9 verified) ----------------
__global__ __launch_bounds__(256) void sc_kernel(const float* __restrict__ x,
                                                 const float* __restrict__ L0,
                                                 const float* __restrict__ L1,
                                                 float* __restrict__ out) {
    __shared__ float l0[256], l1[256];
    __shared__ float xs[4][68];
    const int t = threadIdx.x;
    l0[t] = L0[t];
    l1[t] = L1[t];
    const int g = t >> 6, j = t & 63;
    const int n = blockIdx.x * 4 + g;
    xs[g][j] = x[n * 64 + j];
    __syncthreads();
    float s = 0.f;
    if (j < 16) {
        #pragma unroll
        for (int u = 0; u < 16; ++u) s = fmaf(xs[g][u], l0[u * 16 + j], s);
    } else {
        const int q = j - 16, v = q / 3, k = q - 3 * v;
        #pragma unroll
        for (int u = 0; u < 16; ++u) s = fmaf(xs[g][16 + 3 * u + k], l1[u * 16 + v], s);
    }
    out[n * 64 + j] = 0.25f * s;   // 1/sqrt(MUL)
}

// ---------------- phase B: out[n] = sc(n) + sum of bucketed messages ----------------
__global__ __launch_bounds__(256) void gather_kernel(
    const _Float16* __restrict__ msg, const int* __restrict__ cnt,
    const int* __restrict__ slots, const float* __restrict__ x,
    const float* __restrict__ L0, const float* __restrict__ L1,
    float* __restrict__ out) {
    __shared__ float l0[256], l1[256];
    __shared__ float xs[4][68];
    const int t = threadIdx.x;
    l0[t] = L0[t];
    l1[t] = L1[t];
    const int g = t >> 6, j = t & 63;
    const int n = blockIdx.x * 4 + g;          // 6250 blocks x 4 nodes (one wave each)
    xs[g][j] = x[n * 64 + j];
    __syncthreads();
    // self-connection (round-10 verified math)
    float acc;
    {
        float s = 0.f;
        if (j < 16) {
            #pragma unroll
            for (int u = 0; u < 16; ++u) s = fmaf(xs[g][u], l0[u * 16 + j], s);
        } else {
            const int q = j - 16, v = q / 3, k = q - 3 * v;
            #pragma unroll
            for (int u = 0; u < 16; ++u) s = fmaf(xs[g][16 + 3 * u + k], l1[u * 16 + v], s);
        }
        acc = 0.25f * s;
    }
    // message segment-sum: slot reads are wave-uniform (broadcast); msg row reads
    // are 64 x 2 B contiguous per wave.
    const int deg = min(cnt[n], CAP);
    const int* sl = slots + n * CAP;
    int i = 0;
    for (; i + 4 <= deg; i += 4) {
        const int e0 = sl[i], e1 = sl[i + 1], e2 = sl[i + 2], e3 = sl[i + 3];
        const float v0 = (float)msg[e0 * 64 + j];
        const float v1 = (float)msg[e1 * 64 + j];
        const float v2 = (float)msg[e2 * 64 + j];
        const float v3 = (float)msg[e3 * 64 + j];
        acc += (v0 + v1) + (v2 + v3);
    }
    for (; i < deg; ++i) acc += (float)msg[sl[i] * 64 + j];
    out[n * 64 + j] = acc;
}

// ---------------- phase A: round-9 verified core; combine STORES dense f16 messages ----------------
// 512 threads, 8 waves. Wave w: prog = w>>1, uh = w&1 (u in [uh*8, uh*8+8)).
// Per u, A fragment (h rows mt*16+qm, f16) scaled by coef[e][u] feeds MFMA:
//   C[e][v] = sum_u coef[e][u] * sum_c h[e][c]*W2[c][u*16+v]*scale
// Coef planes: 0: xj0*sh0 | 1: b1 | 2: xj0 | 3+k: xj1[.,k]*sh0
// msg!=nullptr: combine writes msg[(e0+e)*64+j] (plain f16 store) and phase 1
// appends edge ids to per-dst buckets (200k cheap atomics). msg==nullptr:
// exact round-9 behavior (12.8M atomicAdds to out) as fallback.
__global__ __launch_bounds__(512, 4) void edge_kernel(
    const float* __restrict__ x, const float* __restrict__ edge_attr,
    const float* __restrict__ edge_length, const int* __restrict__ edge_src,
    const int* __restrict__ edge_dst, const float* __restrict__ W1,
    const float* __restrict__ W2, float* __restrict__ out,
    _Float16* __restrict__ msg, int* __restrict__ cnt, int* __restrict__ slots) {

    const int t = threadIdx.x;
    const int w = t >> 6;             // wave id 0..7
    const int prog = w >> 1;          // which 16x16-block family of w2
    const int uh = w & 1;             // u-half
    const int qm = t & 15;            // MFMA m/n index
    const int quad = (t >> 4) & 3;    // lane quad within wave

    __shared__ __attribute__((aligned(16))) float lds_h[ET * 72];    // fp32 h, stride 72
    __shared__ __attribute__((aligned(16))) float lds_xj[ET * 68];   // gathered x[src], stride 68
    __shared__ __attribute__((aligned(16))) float lds_cf[6 * ET * 17];  // coef planes [pl][e*17+u]
    __shared__ __attribute__((aligned(16))) float lds_xch[12 * ET * 17];// term exchange [pl][e*17+v]
    __shared__ __attribute__((aligned(16))) float lds_w1t[64 * 8];   // W1^T [c][r]
    __shared__ __attribute__((aligned(16))) float lds_sh[ET * 4];
    __shared__ __attribute__((aligned(16))) float lds_len[ET];
    __shared__ __attribute__((aligned(16))) int   lds_dst[ET];

    constexpr int PL = ET * 17;       // plane stride (544)

    // ---- persistent B fragments: W2 block `prog`, u-half `uh`, pre-scaled f16 ----
    // B-frag layout (16x16x32): lane holds B[k = kf*32 + quad*8 + j][n = qm]
    half8 bfr[8][2];
    {
        float scale = 0.0220970869f;                  // (1/sqrt(64)) * (1/sqrt(32))
        if (prog == 1) scale *= 0.5773502692f;        // INV_SQRT3 folded
        const int kr = quad * 8;
        #pragma unroll
        for (int up = 0; up < 8; ++up) {
            const int col = prog * 256 + (uh * 8 + up) * 16 + qm;
            #pragma unroll
            for (int kf = 0; kf < 2; ++kf) {
                half8 f;
                #pragma unroll
                for (int j = 0; j < 8; ++j) {
                    const int k = kf * 32 + kr + j;
                    f[j] = (_Float16)(W2[k * 1024 + col] * scale);
                }
                bfr[up][kf] = f;
            }
        }
    }
    // W1 -> LDS transposed [c][r]
    {
        const int r = t >> 6, c = t & 63;
        lds_w1t[c * 8 + r] = W1[t];
    }

    for (int tl = 0; tl < NT; ++tl) {
        const int e0 = (blockIdx.x * NT + tl) * ET;
        __syncthreads();   // orders prev-tile combine reads before re-staging

        // ---- phase 1: meta + xj gather (+ bucket append in msg mode) ----
        if (t < ET) {
            const int dst = edge_dst[e0 + t];
            lds_dst[t] = dst;
            lds_len[t] = edge_length[e0 + t];
            const float4v ea = *(const float4v*)(edge_attr + 4 * (e0 + t));
            lds_sh[t * 4 + 0] = ea[0]; lds_sh[t * 4 + 1] = ea[1];
            lds_sh[t * 4 + 2] = ea[2]; lds_sh[t * 4 + 3] = ea[3];
            if (msg) {
                const int pos = atomicAdd(&cnt[dst], 1);
                if (pos < CAP) slots[dst * CAP + pos] = e0 + t;
            }
        }
        {
            const int e_loc = t >> 4;                 // 32 edges x 16 threads
            const int src = edge_src[e0 + e_loc];
            const int c4 = (t & 15) * 4;
            *(float4v*)(&lds_xj[e_loc * 68 + c4]) = *(const float4v*)(x + src * 64 + c4);
        }
        __syncthreads();

        // ---- phase 2: coef planes + h (all 512 threads: e = t&31, u = t>>5) ----
        {
            const int e = t & 31, u = t >> 5;
            const float sh0 = lds_sh[e * 4];
            const float s1x = lds_sh[e * 4 + 1];
            const float s1y = lds_sh[e * 4 + 2];
            const float s1z = lds_sh[e * 4 + 3];
            const float xj0v = lds_xj[e * 68 + u];
            const float x0 = lds_xj[e * 68 + 16 + 3 * u];
            const float x1 = lds_xj[e * 68 + 17 + 3 * u];
            const float x2 = lds_xj[e * 68 + 18 + 3 * u];
            lds_cf[0 * PL + e * 17 + u] = xj0v * sh0;
            lds_cf[1 * PL + e * 17 + u] = fmaf(x0, s1x, fmaf(x1, s1y, x2 * s1z));
            lds_cf[2 * PL + e * 17 + u] = xj0v;
            lds_cf[3 * PL + e * 17 + u] = x0 * sh0;
            lds_cf[4 * PL + e * 17 + u] = x1 * sh0;
            lds_cf[5 * PL + e * 17 + u] = x2 * sh0;
            // h = silu(radial @ W1 / sqrt(8)) for (e, c0..c0+3)
            const int c0 = u * 4;
            const float len = lds_len[e];
            float rad[8];
            #pragma unroll
            for (int r = 0; r < 8; ++r) {
                const float d = len - 0.7142857143f * (float)r;
                rad[r] = __expf(-0.5f * d * d);
            }
            float4v hv;
            #pragma unroll
            for (int i = 0; i < 4; ++i) {
                const float4v wA = *(const float4v*)(&lds_w1t[(c0 + i) * 8]);
                const float4v wB = *(const float4v*)(&lds_w1t[(c0 + i) * 8 + 4]);
                float s = rad[0] * wA[0] + rad[1] * wA[1] + rad[2] * wA[2] + rad[3] * wA[3]
                        + rad[4] * wB[0] + rad[5] * wB[1] + rad[6] * wB[2] + rad[7] * wB[3];
                s *= 0.3535533906f;
                hv[i] = s / (1.f + __expf(-s));
            }
            *(float4v*)(&lds_h[e * 72 + c0]) = hv;
        }
        __syncthreads();

        // ---- phase 3: A fragments for both m-tiles (f16, no lo-split) ----
        half8 ah0[2], ah1[2];
        #pragma unroll
        for (int mt = 0; mt < 2; ++mt) {
            const float* hrow = &lds_h[(mt * 16 + qm) * 72];
            const float4v fa = *(const float4v*)(hrow + quad * 8);
            const float4v fb = *(const float4v*)(hrow + quad * 8 + 4);
            const float4v fc = *(const float4v*)(hrow + 32 + quad * 8);
            const float4v fd = *(const float4v*)(hrow + 32 + quad * 8 + 4);
            #pragma unroll
            for (int j = 0; j < 4; ++j) {
                ah0[mt][j]     = (_Float16)fa[j];
                ah0[mt][4 + j] = (_Float16)fb[j];
                ah1[mt][j]     = (_Float16)fc[j];
                ah1[mt][4 + j] = (_Float16)fd[j];
            }
        }

        // ---- MFMA with per-u coef-scaled A; C = final per-edge term ----
        // C layout per m-tile: row e = mt*16 + quad*4 + r, col v = qm
        if (prog < 3) {
            float4v acc[2];
            acc[0] = (float4v){0.f, 0.f, 0.f, 0.f};
            acc[1] = (float4v){0.f, 0.f, 0.f, 0.f};
            #pragma unroll
            for (int up = 0; up < 8; ++up) {
                const int u = uh * 8 + up;
                #pragma unroll
                for (int mt = 0; mt < 2; ++mt) {
                    const _Float16 c = (_Float16)lds_cf[prog * PL + (mt * 16 + qm) * 17 + u];
                    acc[mt] = __builtin_amdgcn_mfma_f32_16x16x32_f16(h8s(ah0[mt], c), bfr[up][0], acc[mt], 0, 0, 0);
                    acc[mt] = __builtin_amdgcn_mfma_f32_16x16x32_f16(h8s(ah1[mt], c), bfr[up][1], acc[mt], 0, 0, 0);
                }
            }
            float* xb = &lds_xch[w * PL];
            #pragma unroll
            for (int mt = 0; mt < 2; ++mt)
                #pragma unroll
                for (int r = 0; r < 4; ++r)
                    xb[(mt * 16 + quad * 4 + r) * 17 + qm] = acc[mt][r];
        } else {
            float4v a3[2][3];
            #pragma unroll
            for (int mt = 0; mt < 2; ++mt)
                #pragma unroll
                for (int k = 0; k < 3; ++k) a3[mt][k] = (float4v){0.f, 0.f, 0.f, 0.f};
            #pragma unroll
            for (int up = 0; up < 8; ++up) {
                const int u = uh * 8 + up;
                #pragma unroll
                for (int mt = 0; mt < 2; ++mt) {
                    #pragma unroll
                    for (int k = 0; k < 3; ++k) {
                        const _Float16 c = (_Float16)lds_cf[(3 + k) * PL + (mt * 16 + qm) * 17 + u];
                        a3[mt][k] = __builtin_amdgcn_mfma_f32_16x16x32_f16(h8s(ah0[mt], c), bfr[up][0], a3[mt][k], 0, 0, 0);
                        a3[mt][k] = __builtin_amdgcn_mfma_f32_16x16x32_f16(h8s(ah1[mt], c), bfr[up][1], a3[mt][k], 0, 0, 0);
                    }
                }
            }
            #pragma unroll
            for (int k = 0; k < 3; ++k) {
                float* xb = &lds_xch[(6 + uh * 3 + k) * PL];
                #pragma unroll
                for (int mt = 0; mt < 2; ++mt)
                    #pragma unroll
                    for (int r = 0; r < 4; ++r)
                        xb[(mt * 16 + quad * 4 + r) * 17 + qm] = a3[mt][k][r];
            }
        }
        __syncthreads();

        // ---- combine: 4 output elems per thread; dense f16 store (or fallback atomic) ----
        #pragma unroll
        for (int i = 0; i < 4; ++i) {
            const int idx = t + 512 * i;          // 2048 = 32 edges x 64 elems
            const int e = idx >> 6, j = idx & 63;
            float val;
            if (j < 16) {
                val = (lds_xch[0 * PL + e * 17 + j] + lds_xch[1 * PL + e * 17 + j])
                    + (lds_xch[2 * PL + e * 17 + j] + lds_xch[3 * PL + e * 17 + j]);
            } else {
                const int q = j - 16, v = q / 3, k = q - 3 * v;
                const float s2 = lds_xch[4 * PL + e * 17 + v] + lds_xch[5 * PL + e * 17 + v];
                const float s3 = lds_xch[(6 + k) * PL + e * 17 + v]
                               + lds_xch[(9 + k) * PL + e * 17 + v];
                val = fmaf(s2, lds_sh[e * 4 + 1 + k], s3);
            }
            if (msg) {
                msg[(e0 + e) * 64 + j] = (_Float16)val;     // coalesced 128 B/wave
            } else {
                atomicAdd(out + lds_dst[e] * 64 + j, val);  // round-9 fallback
            }
        }
        // next-iteration top barrier orders these LDS reads before re-staging
    }
}

extern "C" void kernel_launch(void* const* d_in, const int* in_sizes, int n_in,
                              void* d_out, int out_size, void* d_ws, size_t ws_size,
                              hipStream_t stream) {
    const float* x           = (const float*)d_in[0];
    const float* edge_attr   = (const float*)d_in[1];
    const float* edge_length = (const float*)d_in[2];
    const int*   edge_src    = (const int*)d_in[3];
    const int*   edge_dst    = (const int*)d_in[4];
    const float* W1          = (const float*)d_in[5];
    const float* W2          = (const float*)d_in[6];
    const float* L0          = (const float*)d_in[7];
    const float* L1          = (const float*)d_in[8];
    float* out = (float*)d_out;

    // ws layout: msg f16 [E*64] | cnt int [25088] | slots int [N_NODES*CAP]
    const size_t msg_bytes  = (size_t)N_EDGES * 64 * 2;          // 25.6 MB
    const size_t cnt_off    = msg_bytes;                          // aligned (25.6e6 % 4 == 0)
    const size_t slots_off  = cnt_off + 25088 * 4;
    const size_t need       = slots_off + (size_t)N_NODES * CAP * 4;  // ~30.5 MB

    if (ws_size >= need) {
        _Float16* msg = (_Float16*)d_ws;
        int* cnt   = (int*)((char*)d_ws + cnt_off);
        int* slots = (int*)((char*)d_ws + slots_off);
        hipMemsetAsync(cnt, 0, 25088 * 4, stream);
        edge_kernel<<<NBLK, 512, 0, stream>>>(
            x, edge_attr, edge_length, edge_src, edge_dst, W1, W2,
            out, msg, cnt, slots);
        gather_kernel<<<N_NODES / 4, 256, 0, stream>>>(
            msg, cnt, slots, x, L0, L1, out);
    } else {
        // fallback: exact round-9 path
        sc_kernel<<<N_NODES / 4, 256, 0, stream>>>(x, L0, L1, out);
        edge_kernel<<<NBLK, 512, 0, stream>>>(
            x, edge_attr, edge_length, edge_src, edge_dst, W1, W2,
            out, nullptr, nullptr, nullptr);
    }
}